// Round 3
// baseline (262.251 us; speedup 1.0000x reference)
//
#include <hip/hip_runtime.h>
#include <hip/hip_bf16.h>

// ============================================================================
// fused stride-2 "transposed conv" + bias + channel-softmax + sigmoid
//
// PAD==OUT_PAD==1 => odd h or odd w outputs are the constant vector
// sigmoid(2*softmax(bias)). Even-even outputs are a dense 4x4 conv:
//   O[n,c,p,q] = sum_{ic,kh,kw} x[n,ic,p-kh,q-kw]*W[c,ic,kh,kw]
//
// R3: 32x32x16 MFMA (A = X positions, B = W channels), W-fragments streamed
// from L2 (no LDS), X hi/lo staged once in LDS (53.5KB, 3 blocks/CU),
// softmax via shfl over lanes 0..31 (D cols = channels), const fill merged.
// Numerics: bf16 hi/lo split (Whi*Xhi + Wlo*Xhi + Whi*Xlo), fp32 acc.
// ============================================================================

typedef __bf16 bf16x8 __attribute__((ext_vector_type(8)));
typedef float  f32x16 __attribute__((ext_vector_type(16)));
typedef unsigned short ushort_t;

#define TILE_P 8
#define TILE_Q 16
#define PATCH_R 11                    // TILE_P + 3
#define PATCH_C 19                    // TILE_Q + 3
#define XELEMS (PATCH_R*PATCH_C*64)   // 13376 bf16 per plane
#define XLO_BYTES (XELEMS*2)          // 26752
#define SMEM_BYTES (XELEMS*2*2)       // 53504 -> 3 blocks/CU
#define WSW_BYTES (16*4*4*2*64*16)    // 524288 bytes of W fragments

// ---- prep: weight -> 32x32x16 B-fragment order, bf16 hi/lo -----------------
// frag f = ((tap*4+icg)*4+Nt)*2+hl, 1KB each (lane*16B).
// B-frag: lane l holds B[k=(l>>5)*8+i][col=l&31]; col=cout=Nt*32+(l&31),
// k -> ic = icg*16 + (l>>5)*8 + i  (same (l>>5,i) class as the A-side).
__global__ void prep_w_kernel(const float* __restrict__ w, ushort_t* __restrict__ wsW) {
    int slot = blockIdx.x * 256 + threadIdx.x;      // 32768 slots
    int lane = slot & 63;
    int hl   = (slot >> 6) & 1;
    int Nt   = (slot >> 7) & 3;
    int icg  = (slot >> 9) & 3;
    int tap  = slot >> 11;
    int kh = tap >> 2, kw = tap & 3;
    int cout = Nt * 32 + (lane & 31);
    int icb  = icg * 16 + (lane >> 5) * 8;
    bf16x8 v;
#pragma unroll
    for (int i = 0; i < 8; ++i) {
        float f = w[((cout * 64 + icb + i) * 4 + kh) * 4 + kw];
        __bf16 h = (__bf16)f;
        v[i] = hl ? (__bf16)(f - (float)h) : h;
    }
    *(bf16x8*)(wsW + (size_t)slot * 8) = v;   // slot*16 bytes
}

// ---- prep: const vector sigmoid(2*softmax(bias)) ---------------------------
__global__ void prep_const_kernel(const float* __restrict__ bias, float* __restrict__ wsc) {
    __shared__ float red[128];
    int t = threadIdx.x;
    red[t] = bias[t];
    __syncthreads();
    float m = -3.4e38f;
    for (int i = 0; i < 128; ++i) m = fmaxf(m, red[i]);
    float e = __expf(red[t] - m);
    __syncthreads();
    red[t] = e;
    __syncthreads();
    float s = 0.f;
    for (int i = 0; i < 128; ++i) s += red[i];
    float v = e / s;
    wsc[t] = 1.0f / (1.0f + __expf(-2.0f * v));
}

// ---- main ------------------------------------------------------------------
__launch_bounds__(256, 3)
__global__ void conv_main_kernel(const float* __restrict__ x,
                                 const float* __restrict__ bias,
                                 const ushort_t* __restrict__ wsW,
                                 const float* __restrict__ wsc,
                                 float* __restrict__ out) {
    extern __shared__ char smem[];
    ushort_t* xs = (ushort_t*)smem;

    const int tid = threadIdx.x;
    const int n   = blockIdx.z;
    const int p0  = blockIdx.y * TILE_P;
    const int q0  = blockIdx.x * TILE_Q;

    const int lane = tid & 63;
    const int wv   = tid >> 6;
    const int l31  = lane & 31;
    const int lhi  = lane >> 5;

    // ---- stage X patch hi+lo, single pass; lanes sweep cols (coalesced) ----
    const float* xg = x + (size_t)n * 262144;
    for (int grp = tid; grp < PATCH_R * PATCH_C * 8; grp += 256) {
        int r   = grp / (PATCH_C * 8);
        int rem = grp - r * (PATCH_C * 8);
        int g   = rem / PATCH_C;
        int c   = rem - g * PATCH_C;
        int row = p0 + r - 3;
        int col = q0 + c - 3;
        bool ok = (row >= 0) & (row < 64) & (col >= 0) & (col < 64);
        const float* src = xg + (g * 8) * 4096 + row * 64 + col;
        bf16x8 hi, lo;
#pragma unroll
        for (int i = 0; i < 8; ++i) {
            float f = ok ? src[i * 4096] : 0.0f;
            __bf16 h = (__bf16)f;
            hi[i] = h;
            lo[i] = (__bf16)(f - (float)h);
        }
        int slot = ((r * PATCH_C + c) * 8 + (g ^ (c & 7))) * 8;     // elem idx
        *(bf16x8*)(xs + slot)          = hi;
        *(bf16x8*)(xs + XELEMS + slot) = lo;
    }
    __syncthreads();

    // ---- K loop: 64 Ksteps (16 taps x 4 ic16-groups) -----------------------
    const int qA  = l31 & 15;          // A row -> position q within tile
    const int prw = l31 >> 4;          // A row -> p-row within Mtile
    const int MtB = (wv >> 1) * 2;     // this wave: Mtiles MtB, MtB+1
    const int NtB = (wv & 1) * 2;      // this wave: Ntiles NtB, NtB+1
    const bool mv0 = (p0 + (MtB + 0) * 2) < 65;
    const bool mv1 = (p0 + (MtB + 1) * 2) < 65;

    f32x16 acc[2][2];
#pragma unroll
    for (int m = 0; m < 2; ++m)
#pragma unroll
        for (int nt = 0; nt < 2; ++nt)
            acc[m][nt] = (f32x16)(0.0f);

    const char* wbase = (const char*)wsW + NtB * 2048 + lane * 16;
    const char* xsc   = (const char*)smem;

#pragma unroll 2
    for (int ks = 0; ks < 64; ++ks) {
        int tap = ks >> 2, icg = ks & 3;
        int kh = tap >> 2, kw = tap & 3;
        int pc = qA + 3 - kw;
        int pr = (MtB * 2 + prw) + 3 - kh;
        int g8 = icg * 2 + lhi;
        int addr = ((((pr * PATCH_C + pc) << 3) + (g8 ^ (pc & 7))) << 4);  // bytes

        const char* wp = wbase + ks * 8192;
        bf16x8 w0h = *(const bf16x8*)(wp);
        bf16x8 w0l = *(const bf16x8*)(wp + 1024);
        bf16x8 w1h = *(const bf16x8*)(wp + 2048);
        bf16x8 w1l = *(const bf16x8*)(wp + 3072);

        if (mv0) {
            bf16x8 xh = *(const bf16x8*)(xsc + addr);
            bf16x8 xl = *(const bf16x8*)(xsc + addr + XLO_BYTES);
            acc[0][0] = __builtin_amdgcn_mfma_f32_32x32x16_bf16(xh, w0h, acc[0][0], 0, 0, 0);
            acc[0][1] = __builtin_amdgcn_mfma_f32_32x32x16_bf16(xh, w1h, acc[0][1], 0, 0, 0);
            acc[0][0] = __builtin_amdgcn_mfma_f32_32x32x16_bf16(xh, w0l, acc[0][0], 0, 0, 0);
            acc[0][1] = __builtin_amdgcn_mfma_f32_32x32x16_bf16(xh, w1l, acc[0][1], 0, 0, 0);
            acc[0][0] = __builtin_amdgcn_mfma_f32_32x32x16_bf16(xl, w0h, acc[0][0], 0, 0, 0);
            acc[0][1] = __builtin_amdgcn_mfma_f32_32x32x16_bf16(xl, w1h, acc[0][1], 0, 0, 0);
        }
        if (mv1) {
            bf16x8 xh = *(const bf16x8*)(xsc + addr + 4864);              // +2 p-rows
            bf16x8 xl = *(const bf16x8*)(xsc + addr + 4864 + XLO_BYTES);
            acc[1][0] = __builtin_amdgcn_mfma_f32_32x32x16_bf16(xh, w0h, acc[1][0], 0, 0, 0);
            acc[1][1] = __builtin_amdgcn_mfma_f32_32x32x16_bf16(xh, w1h, acc[1][1], 0, 0, 0);
            acc[1][0] = __builtin_amdgcn_mfma_f32_32x32x16_bf16(xh, w0l, acc[1][0], 0, 0, 0);
            acc[1][1] = __builtin_amdgcn_mfma_f32_32x32x16_bf16(xh, w1l, acc[1][1], 0, 0, 0);
            acc[1][0] = __builtin_amdgcn_mfma_f32_32x32x16_bf16(xl, w0h, acc[1][0], 0, 0, 0);
            acc[1][1] = __builtin_amdgcn_mfma_f32_32x32x16_bf16(xl, w1h, acc[1][1], 0, 0, 0);
        }
    }

    // ---- bias add (D col = channel = l31-based -> scalar splat per nt) -----
    {
        float bv0 = bias[(NtB + 0) * 32 + l31];
        float bv1 = bias[(NtB + 1) * 32 + l31];
#pragma unroll
        for (int m = 0; m < 2; ++m)
#pragma unroll
            for (int j = 0; j < 16; ++j) {
                acc[m][0][j] += bv0;
                acc[m][1][j] += bv1;
            }
    }

    __syncthreads();                    // X planes dead -> overlay reduce bufs
    float* red1 = (float*)smem;         // [128 pos][2 wave-halves] max
    float* red2 = (float*)(smem + 1024);// [128 pos][2] sum

    // ---- pass A: per-position max over this wave's 64 channels -> red1 ----
#pragma unroll
    for (int m = 0; m < 2; ++m) {
#pragma unroll
        for (int reg = 0; reg < 16; ++reg) {
            int r32 = (reg & 3) + 8 * (reg >> 2) + 4 * lhi;   // D row = pos in Mt
            float v = fmaxf(acc[m][0][reg], acc[m][1][reg]);
            v = fmaxf(v, __shfl_xor(v, 1));
            v = fmaxf(v, __shfl_xor(v, 2));
            v = fmaxf(v, __shfl_xor(v, 4));
            v = fmaxf(v, __shfl_xor(v, 8));
            v = fmaxf(v, __shfl_xor(v, 16));
            if (l31 == reg) red1[((MtB + m) * 32 + r32) * 2 + (wv & 1)] = v;
        }
    }
    __syncthreads();

    // ---- pass B: exp + per-position sum -> red2 ----------------------------
#pragma unroll
    for (int m = 0; m < 2; ++m) {
#pragma unroll
        for (int reg = 0; reg < 16; ++reg) {
            int r32 = (reg & 3) + 8 * (reg >> 2) + 4 * lhi;
            int pos = (MtB + m) * 32 + r32;
            float gm = fmaxf(red1[pos * 2], red1[pos * 2 + 1]);
            float e0 = __expf(acc[m][0][reg] - gm);
            float e1 = __expf(acc[m][1][reg] - gm);
            acc[m][0][reg] = e0;
            acc[m][1][reg] = e1;
            float s = e0 + e1;
            s += __shfl_xor(s, 1);
            s += __shfl_xor(s, 2);
            s += __shfl_xor(s, 4);
            s += __shfl_xor(s, 8);
            s += __shfl_xor(s, 16);
            if (l31 == reg) red2[pos * 2 + (wv & 1)] = s;
        }
    }
    __syncthreads();

    // ---- pass C: normalize, sigmoid, store (even-h rows, float2 pairs) -----
    {
        float cv0 = wsc[(NtB + 0) * 32 + l31];
        float cv1 = wsc[(NtB + 1) * 32 + l31];
        const size_t cstride = (size_t)129 * 129;   // per-channel plane
#pragma unroll
        for (int m = 0; m < 2; ++m) {
#pragma unroll
            for (int reg = 0; reg < 16; ++reg) {
                int r32 = (reg & 3) + 8 * (reg >> 2) + 4 * lhi;
                int pos = (MtB + m) * 32 + r32;
                int p  = p0 + (pos >> 4);
                int qq = q0 + (pos & 15);
                if (p < 65 && qq < 65) {
                    float inv = 1.0f / (red2[pos * 2] + red2[pos * 2 + 1]);
                    float v0 = acc[m][0][reg] * inv;
                    float v1 = acc[m][1][reg] * inv;
                    float sg0 = 1.0f / (1.0f + __expf(-2.0f * v0));
                    float sg1 = 1.0f / (1.0f + __expf(-2.0f * v1));
                    size_t o0 = ((size_t)(n * 128 + (NtB + 0) * 32 + l31) * 129 + 2 * p) * 129 + 2 * qq;
                    size_t o1 = o0 + 32 * cstride;
                    if (qq < 64) {
                        float2 a = {sg0, cv0};
                        float2 b = {sg1, cv1};
                        *(float2*)(out + o0) = a;
                        *(float2*)(out + o1) = b;
                    } else {
                        out[o0] = sg0;
                        out[o1] = sg1;
                    }
                }
            }
        }
    }

    // ---- const fill for this block's odd-h rows (coalesced 128B runs) ------
    {
        int ro = tid >> 5;              // 0..7 -> p row
        int cc = 2 * q0 + (tid & 31);   // output col
        int p  = p0 + ro;
        if (p < 64 && cc < 129) {
            int oh = 2 * p + 1;
            float* obase = out + ((size_t)n * 128 * 129 + oh) * 129 + cc;
            for (int c = 0; c < 128; ++c) {
                obase[(size_t)c * 129 * 129] = wsc[c];
            }
        }
    }
}

extern "C" void kernel_launch(void* const* d_in, const int* in_sizes, int n_in,
                              void* d_out, int out_size, void* d_ws, size_t ws_size,
                              hipStream_t stream) {
    const float* x    = (const float*)d_in[0];
    const float* w    = (const float*)d_in[1];
    const float* bias = (const float*)d_in[2];
    float* out = (float*)d_out;

    ushort_t* wsW = (ushort_t*)d_ws;                          // 512 KB
    float* wsc    = (float*)((char*)d_ws + WSW_BYTES);        // 512 B

    (void)hipFuncSetAttribute((const void*)conv_main_kernel,
                              hipFuncAttributeMaxDynamicSharedMemorySize, SMEM_BYTES);

    prep_w_kernel<<<128, 256, 0, stream>>>(w, wsW);
    prep_const_kernel<<<1, 128, 0, stream>>>(bias, wsc);

    dim3 grid(5, 9, 32);   // q-tiles, p-tiles, n
    conv_main_kernel<<<grid, 256, SMEM_BYTES, stream>>>(x, bias, wsW, wsc, out);
}

// Round 4
// 254.814 us; speedup vs baseline: 1.0292x; 1.0292x over previous
//
#include <hip/hip_runtime.h>
#include <hip/hip_bf16.h>

// ============================================================================
// fused stride-2 "transposed conv" + bias + channel-softmax + sigmoid
//
// PAD==OUT_PAD==1 => odd h or odd w outputs are the constant vector
// sigmoid(2*softmax(bias)). Even-even outputs are a dense 4x4 conv:
//   O[n,c,p,q] = sum_{ic,kh,kw} x[n,ic,p-kh,q-kw]*W[c,ic,kh,kw]
//
// R4: R3's 32x32x16 MFMA K-loop (W streamed from L2, X hi/lo in LDS) +
// write-friendly epilogue: odd-row const fill merged as FULL 516B row writes
// (183 rows/block), pass C float2 pairs. Numerics: bf16 hi/lo split.
// ============================================================================

typedef __bf16 bf16x8 __attribute__((ext_vector_type(8)));
typedef float  f32x16 __attribute__((ext_vector_type(16)));
typedef unsigned short ushort_t;

#define TILE_P 8
#define TILE_Q 16
#define PATCH_R 11                    // TILE_P + 3
#define PATCH_C 19                    // TILE_Q + 3
#define XELEMS (PATCH_R*PATCH_C*64)   // 13376 bf16 per plane
#define XLO_BYTES (XELEMS*2)          // 26752
#define SMEM_BYTES (XELEMS*2*2)       // 53504 -> 3 blocks/CU
#define WSW_BYTES (16*4*4*2*64*16)    // 524288 bytes of W fragments
#define ODD_ROWS (32*128*64)          // 262144 odd output rows
#define ROWS_PER_BLOCK 183            // ceil(262144/1440)

// ---- prep: weight -> 32x32x16 B-fragment order, bf16 hi/lo -----------------
__global__ void prep_w_kernel(const float* __restrict__ w, ushort_t* __restrict__ wsW) {
    int slot = blockIdx.x * 256 + threadIdx.x;      // 32768 slots
    int lane = slot & 63;
    int hl   = (slot >> 6) & 1;
    int Nt   = (slot >> 7) & 3;
    int icg  = (slot >> 9) & 3;
    int tap  = slot >> 11;
    int kh = tap >> 2, kw = tap & 3;
    int cout = Nt * 32 + (lane & 31);
    int icb  = icg * 16 + (lane >> 5) * 8;
    bf16x8 v;
#pragma unroll
    for (int i = 0; i < 8; ++i) {
        float f = w[((cout * 64 + icb + i) * 4 + kh) * 4 + kw];
        __bf16 h = (__bf16)f;
        v[i] = hl ? (__bf16)(f - (float)h) : h;
    }
    *(bf16x8*)(wsW + (size_t)slot * 8) = v;   // slot*16 bytes
}

// ---- prep: const vector sigmoid(2*softmax(bias)) ---------------------------
__global__ void prep_const_kernel(const float* __restrict__ bias, float* __restrict__ wsc) {
    __shared__ float red[128];
    int t = threadIdx.x;
    red[t] = bias[t];
    __syncthreads();
    float m = -3.4e38f;
    for (int i = 0; i < 128; ++i) m = fmaxf(m, red[i]);
    float e = __expf(red[t] - m);
    __syncthreads();
    red[t] = e;
    __syncthreads();
    float s = 0.f;
    for (int i = 0; i < 128; ++i) s += red[i];
    float v = e / s;
    wsc[t] = 1.0f / (1.0f + __expf(-2.0f * v));
}

// ---- main ------------------------------------------------------------------
__launch_bounds__(256, 3)
__global__ void conv_main_kernel(const float* __restrict__ x,
                                 const float* __restrict__ bias,
                                 const ushort_t* __restrict__ wsW,
                                 const float* __restrict__ wsc,
                                 float* __restrict__ out) {
    extern __shared__ char smem[];
    ushort_t* xs = (ushort_t*)smem;

    const int tid = threadIdx.x;
    const int n   = blockIdx.z;
    const int p0  = blockIdx.y * TILE_P;
    const int q0  = blockIdx.x * TILE_Q;

    const int lane = tid & 63;
    const int wv   = tid >> 6;
    const int l31  = lane & 31;
    const int lhi  = lane >> 5;

    // ---- stage X patch hi+lo, single pass ----------------------------------
    const float* xg = x + (size_t)n * 262144;
    for (int grp = tid; grp < PATCH_R * PATCH_C * 8; grp += 256) {
        int r   = grp / (PATCH_C * 8);
        int rem = grp - r * (PATCH_C * 8);
        int g   = rem / PATCH_C;
        int c   = rem - g * PATCH_C;
        int row = p0 + r - 3;
        int col = q0 + c - 3;
        bool ok = (row >= 0) & (row < 64) & (col >= 0) & (col < 64);
        const float* src = xg + (g * 8) * 4096 + row * 64 + col;
        bf16x8 hi, lo;
#pragma unroll
        for (int i = 0; i < 8; ++i) {
            float f = ok ? src[i * 4096] : 0.0f;
            __bf16 h = (__bf16)f;
            hi[i] = h;
            lo[i] = (__bf16)(f - (float)h);
        }
        int slot = ((r * PATCH_C + c) * 8 + (g ^ (c & 7))) * 8;     // elem idx
        *(bf16x8*)(xs + slot)          = hi;
        *(bf16x8*)(xs + XELEMS + slot) = lo;
    }
    __syncthreads();

    // ---- K loop: 64 Ksteps (16 taps x 4 ic16-groups) -----------------------
    const int qA  = l31 & 15;          // A row -> position q within tile
    const int prw = l31 >> 4;          // A row -> p-row within Mtile
    const int MtB = (wv >> 1) * 2;     // this wave: Mtiles MtB, MtB+1
    const int NtB = (wv & 1) * 2;      // this wave: Ntiles NtB, NtB+1
    const bool mv0 = (p0 + (MtB + 0) * 2) < 65;
    const bool mv1 = (p0 + (MtB + 1) * 2) < 65;

    f32x16 acc[2][2];
#pragma unroll
    for (int m = 0; m < 2; ++m)
#pragma unroll
        for (int nt = 0; nt < 2; ++nt)
            acc[m][nt] = (f32x16)(0.0f);

    const char* wbase = (const char*)wsW + NtB * 2048 + lane * 16;
    const char* xsc   = (const char*)smem;

#pragma unroll 2
    for (int ks = 0; ks < 64; ++ks) {
        int tap = ks >> 2, icg = ks & 3;
        int kh = tap >> 2, kw = tap & 3;
        int pc = qA + 3 - kw;
        int pr = (MtB * 2 + prw) + 3 - kh;
        int g8 = icg * 2 + lhi;
        int addr = ((((pr * PATCH_C + pc) << 3) + (g8 ^ (pc & 7))) << 4);  // bytes

        const char* wp = wbase + ks * 8192;
        bf16x8 w0h = *(const bf16x8*)(wp);
        bf16x8 w0l = *(const bf16x8*)(wp + 1024);
        bf16x8 w1h = *(const bf16x8*)(wp + 2048);
        bf16x8 w1l = *(const bf16x8*)(wp + 3072);

        if (mv0) {
            bf16x8 xh = *(const bf16x8*)(xsc + addr);
            bf16x8 xl = *(const bf16x8*)(xsc + addr + XLO_BYTES);
            acc[0][0] = __builtin_amdgcn_mfma_f32_32x32x16_bf16(xh, w0h, acc[0][0], 0, 0, 0);
            acc[0][1] = __builtin_amdgcn_mfma_f32_32x32x16_bf16(xh, w1h, acc[0][1], 0, 0, 0);
            acc[0][0] = __builtin_amdgcn_mfma_f32_32x32x16_bf16(xh, w0l, acc[0][0], 0, 0, 0);
            acc[0][1] = __builtin_amdgcn_mfma_f32_32x32x16_bf16(xh, w1l, acc[0][1], 0, 0, 0);
            acc[0][0] = __builtin_amdgcn_mfma_f32_32x32x16_bf16(xl, w0h, acc[0][0], 0, 0, 0);
            acc[0][1] = __builtin_amdgcn_mfma_f32_32x32x16_bf16(xl, w1h, acc[0][1], 0, 0, 0);
        }
        if (mv1) {
            bf16x8 xh = *(const bf16x8*)(xsc + addr + 4864);              // +2 p-rows
            bf16x8 xl = *(const bf16x8*)(xsc + addr + 4864 + XLO_BYTES);
            acc[1][0] = __builtin_amdgcn_mfma_f32_32x32x16_bf16(xh, w0h, acc[1][0], 0, 0, 0);
            acc[1][1] = __builtin_amdgcn_mfma_f32_32x32x16_bf16(xh, w1h, acc[1][1], 0, 0, 0);
            acc[1][0] = __builtin_amdgcn_mfma_f32_32x32x16_bf16(xh, w0l, acc[1][0], 0, 0, 0);
            acc[1][1] = __builtin_amdgcn_mfma_f32_32x32x16_bf16(xh, w1l, acc[1][1], 0, 0, 0);
            acc[1][0] = __builtin_amdgcn_mfma_f32_32x32x16_bf16(xl, w0h, acc[1][0], 0, 0, 0);
            acc[1][1] = __builtin_amdgcn_mfma_f32_32x32x16_bf16(xl, w1h, acc[1][1], 0, 0, 0);
        }
    }

    // ---- bias add ----------------------------------------------------------
    {
        float bv0 = bias[(NtB + 0) * 32 + l31];
        float bv1 = bias[(NtB + 1) * 32 + l31];
#pragma unroll
        for (int m = 0; m < 2; ++m)
#pragma unroll
            for (int j = 0; j < 16; ++j) {
                acc[m][0][j] += bv0;
                acc[m][1][j] += bv1;
            }
    }

    __syncthreads();                    // X planes dead -> overlay reduce bufs
    float* red1  = (float*)smem;        // [128 pos][2] max
    float* red2  = (float*)(smem + 1024);// [128 pos][2] sum
    float* cfill = (float*)(smem + 2048);// [128] const vector

    // ---- pass A: per-position max over this wave's 64 channels -> red1 ----
#pragma unroll
    for (int m = 0; m < 2; ++m) {
#pragma unroll
        for (int reg = 0; reg < 16; ++reg) {
            int r32 = (reg & 3) + 8 * (reg >> 2) + 4 * lhi;   // D row = pos in Mt
            float v = fmaxf(acc[m][0][reg], acc[m][1][reg]);
            v = fmaxf(v, __shfl_xor(v, 1));
            v = fmaxf(v, __shfl_xor(v, 2));
            v = fmaxf(v, __shfl_xor(v, 4));
            v = fmaxf(v, __shfl_xor(v, 8));
            v = fmaxf(v, __shfl_xor(v, 16));
            if (l31 == reg) red1[((MtB + m) * 32 + r32) * 2 + (wv & 1)] = v;
        }
    }
    __syncthreads();

    // ---- pass B: exp + per-position sum -> red2 ----------------------------
#pragma unroll
    for (int m = 0; m < 2; ++m) {
#pragma unroll
        for (int reg = 0; reg < 16; ++reg) {
            int r32 = (reg & 3) + 8 * (reg >> 2) + 4 * lhi;
            int pos = (MtB + m) * 32 + r32;
            float gm = fmaxf(red1[pos * 2], red1[pos * 2 + 1]);
            float e0 = __expf(acc[m][0][reg] - gm);
            float e1 = __expf(acc[m][1][reg] - gm);
            acc[m][0][reg] = e0;
            acc[m][1][reg] = e1;
            float s = e0 + e1;
            s += __shfl_xor(s, 1);
            s += __shfl_xor(s, 2);
            s += __shfl_xor(s, 4);
            s += __shfl_xor(s, 8);
            s += __shfl_xor(s, 16);
            if (l31 == reg) red2[pos * 2 + (wv & 1)] = s;
        }
    }
    __syncthreads();

    if (tid < 128) cfill[tid] = wsc[tid];   // stage const vec (region disjoint)

    // ---- pass C: normalize, sigmoid, store (even-h rows, float2 pairs) -----
    {
        float cv0 = wsc[(NtB + 0) * 32 + l31];
        float cv1 = wsc[(NtB + 1) * 32 + l31];
        const size_t cstride = (size_t)129 * 129;   // per-channel plane
#pragma unroll
        for (int m = 0; m < 2; ++m) {
#pragma unroll
            for (int reg = 0; reg < 16; ++reg) {
                int r32 = (reg & 3) + 8 * (reg >> 2) + 4 * lhi;
                int pos = (MtB + m) * 32 + r32;
                int p  = p0 + (pos >> 4);
                int qq = q0 + (pos & 15);
                if (p < 65 && qq < 65) {
                    float inv = 1.0f / (red2[pos * 2] + red2[pos * 2 + 1]);
                    float v0 = acc[m][0][reg] * inv;
                    float v1 = acc[m][1][reg] * inv;
                    float sg0 = 1.0f / (1.0f + __expf(-2.0f * v0));
                    float sg1 = 1.0f / (1.0f + __expf(-2.0f * v1));
                    size_t o0 = ((size_t)(n * 128 + (NtB + 0) * 32 + l31) * 129 + 2 * p) * 129 + 2 * qq;
                    size_t o1 = o0 + 32 * cstride;
                    if (qq < 64) {
                        float2 a = {sg0, cv0};
                        float2 b = {sg1, cv1};
                        *(float2*)(out + o0) = a;
                        *(float2*)(out + o1) = b;
                    } else {
                        out[o0] = sg0;
                        out[o1] = sg1;
                    }
                }
            }
        }
    }
    __syncthreads();

    // ---- merged odd-row const fill: 183 FULL 516B rows per block -----------
    // row r -> n = r>>13, c = (r>>6)&127, oh = 2*(r&63)+1; 129 floats each.
    {
        int rbase = (blockIdx.z * 45 + blockIdx.y * 5 + blockIdx.x) * ROWS_PER_BLOCK;
        int t    = tid & 127;           // column 0..127
        int half = tid >> 7;            // 2 rows per iteration
        for (int i = half; i < ROWS_PER_BLOCK; i += 2) {
            int r = rbase + i;
            if (r < ODD_ROWS) {
                int n2 = r >> 13;
                int c2 = (r >> 6) & 127;
                int oh = ((r & 63) << 1) + 1;
                float v = cfill[c2];
                size_t base = ((size_t)(n2 * 128 + c2) * 129 + oh) * 129;
                out[base + t] = v;
                if (t == 127) out[base + 128] = v;
            }
        }
    }
}

extern "C" void kernel_launch(void* const* d_in, const int* in_sizes, int n_in,
                              void* d_out, int out_size, void* d_ws, size_t ws_size,
                              hipStream_t stream) {
    const float* x    = (const float*)d_in[0];
    const float* w    = (const float*)d_in[1];
    const float* bias = (const float*)d_in[2];
    float* out = (float*)d_out;

    ushort_t* wsW = (ushort_t*)d_ws;                          // 512 KB
    float* wsc    = (float*)((char*)d_ws + WSW_BYTES);        // 512 B

    (void)hipFuncSetAttribute((const void*)conv_main_kernel,
                              hipFuncAttributeMaxDynamicSharedMemorySize, SMEM_BYTES);

    prep_w_kernel<<<128, 256, 0, stream>>>(w, wsW);
    prep_const_kernel<<<1, 128, 0, stream>>>(bias, wsc);

    dim3 grid(5, 9, 32);   // q-tiles, p-tiles, n
    conv_main_kernel<<<grid, 256, SMEM_BYTES, stream>>>(x, bias, wsW, wsc, out);
}

// Round 5
// 200.168 us; speedup vs baseline: 1.3102x; 1.2730x over previous
//
#include <hip/hip_runtime.h>
#include <hip/hip_bf16.h>

// ============================================================================
// fused stride-2 "transposed conv" + bias + channel-softmax + sigmoid
//
// PAD==OUT_PAD==1 => odd h or odd w outputs are the constant vector
// sigmoid(2*softmax(bias)). Even-even outputs are a dense 4x4 conv:
//   O[n,c,p,q] = sum_{ic,kh,kw} x[n,ic,p-kh,q-kw]*W[c,ic,kh,kw]
//
// R5: operand swap vs R4 — A=W (row=cout), B=X (col=position) so D cols are
// positions: epilogue stores are 128B-contiguous per 16 lanes (R4 scattered
// 8B/lane across 32 channel planes -> 2.3x write amp + store-queue stalls).
// Softmax now in-lane over regs. TILE_P=4 -> 34KB LDS -> 4 blocks/CU.
// Numerics: bf16 hi/lo split (Whi*Xhi + Wlo*Xhi + Whi*Xlo), fp32 acc.
// ============================================================================

typedef __bf16 bf16x8 __attribute__((ext_vector_type(8)));
typedef float  f32x4  __attribute__((ext_vector_type(4)));
typedef float  f32x16 __attribute__((ext_vector_type(16)));
typedef unsigned short ushort_t;

#define TILE_P 4
#define TILE_Q 16
#define PATCH_R 7                     // TILE_P + 3
#define PATCH_C 19                    // TILE_Q + 3
#define XELEMS (PATCH_R*PATCH_C*64)   // 8512 bf16 per plane
#define XLO_BYTES (XELEMS*2)          // 17024
#define SMEM_BYTES (XELEMS*2*2)       // 34048 -> 4 blocks/CU
#define WSW_BYTES (16*4*4*2*64*16)    // 524288 bytes of W fragments
#define ODD_ROWS (32*128*64)          // 262144 odd output rows
#define NBLOCKS (5*17*32)             // 2720
#define ROWS_PER_BLOCK 97             // ceil(262144/2720)

// ---- prep: weight -> 32x32 fragment order, bf16 hi/lo (same bytes as R4) ---
// frag f = ((tap*4+icg)*4+Mt)*2+hl, 1KB each; lane l holds
// W[cout=Mt*32+(l&31)][ic=icg*16+(l>>5)*8+i]  (A-operand: row=l&31, k slice).
__global__ void prep_w_kernel(const float* __restrict__ w, ushort_t* __restrict__ wsW) {
    int slot = blockIdx.x * 256 + threadIdx.x;      // 32768 slots
    int lane = slot & 63;
    int hl   = (slot >> 6) & 1;
    int Mt   = (slot >> 7) & 3;
    int icg  = (slot >> 9) & 3;
    int tap  = slot >> 11;
    int kh = tap >> 2, kw = tap & 3;
    int cout = Mt * 32 + (lane & 31);
    int icb  = icg * 16 + (lane >> 5) * 8;
    bf16x8 v;
#pragma unroll
    for (int i = 0; i < 8; ++i) {
        float f = w[((cout * 64 + icb + i) * 4 + kh) * 4 + kw];
        __bf16 h = (__bf16)f;
        v[i] = hl ? (__bf16)(f - (float)h) : h;
    }
    *(bf16x8*)(wsW + (size_t)slot * 8) = v;   // slot*16 bytes
}

// ---- prep: const vector sigmoid(2*softmax(bias)) ---------------------------
__global__ void prep_const_kernel(const float* __restrict__ bias, float* __restrict__ wsc) {
    __shared__ float red[128];
    int t = threadIdx.x;
    red[t] = bias[t];
    __syncthreads();
    float m = -3.4e38f;
    for (int i = 0; i < 128; ++i) m = fmaxf(m, red[i]);
    float e = __expf(red[t] - m);
    __syncthreads();
    red[t] = e;
    __syncthreads();
    float s = 0.f;
    for (int i = 0; i < 128; ++i) s += red[i];
    float v = e / s;
    wsc[t] = 1.0f / (1.0f + __expf(-2.0f * v));
}

// ---- main ------------------------------------------------------------------
__launch_bounds__(256, 4)
__global__ void conv_main_kernel(const float* __restrict__ x,
                                 const float* __restrict__ bias,
                                 const ushort_t* __restrict__ wsW,
                                 const float* __restrict__ wsc,
                                 float* __restrict__ out) {
    extern __shared__ char smem[];
    ushort_t* xs = (ushort_t*)smem;

    const int tid = threadIdx.x;
    const int n   = blockIdx.z;
    const int p0  = blockIdx.y * TILE_P;
    const int q0  = blockIdx.x * TILE_Q;

    const int lane = tid & 63;
    const int wv   = tid >> 6;       // wave id = Mtile (32 couts)
    const int l31  = lane & 31;
    const int lhi  = lane >> 5;
    const int qA   = l31 & 15;       // B col -> q offset
    const int dp   = l31 >> 4;       // B col -> p offset within Ntile

    // ---- stage X patch hi+lo, single pass ----------------------------------
    const float* xg = x + (size_t)n * 262144;
    for (int grp = tid; grp < PATCH_R * PATCH_C * 8; grp += 256) {
        int r   = grp / (PATCH_C * 8);
        int rem = grp - r * (PATCH_C * 8);
        int g   = rem / PATCH_C;
        int c   = rem - g * PATCH_C;
        int row = p0 + r - 3;
        int col = q0 + c - 3;
        bool ok = (row >= 0) & (row < 64) & (col >= 0) & (col < 64);
        const float* src = xg + (g * 8) * 4096 + row * 64 + col;
        bf16x8 hi, lo;
#pragma unroll
        for (int i = 0; i < 8; ++i) {
            float f = ok ? src[i * 4096] : 0.0f;
            __bf16 h = (__bf16)f;
            hi[i] = h;
            lo[i] = (__bf16)(f - (float)h);
        }
        int slot = ((r * PATCH_C + c) * 8 + (g ^ (c & 7))) * 8;     // elem idx
        *(bf16x8*)(xs + slot)          = hi;
        *(bf16x8*)(xs + XELEMS + slot) = lo;
    }
    __syncthreads();

    // ---- K loop: 64 Ksteps (16 taps x 4 ic16-groups) -----------------------
    const bool nt1v = (p0 + 2) < 65;   // Ntile 1 produces any valid p?

    f32x16 acc[2];
    acc[0] = (f32x16)(0.0f);
    acc[1] = (f32x16)(0.0f);

    const char* wbase = (const char*)wsW + wv * 2048 + lane * 16;
    const char* xsc   = (const char*)smem;

#pragma unroll 2
    for (int ks = 0; ks < 64; ++ks) {
        int tap = ks >> 2, icg = ks & 3;
        int kh = tap >> 2, kw = tap & 3;
        int pc = qA + 3 - kw;
        int pr = dp + 3 - kh;
        int g8 = icg * 2 + lhi;
        int addr = ((((pr * PATCH_C + pc) << 3) + (g8 ^ (pc & 7))) << 4);  // bytes

        const char* wp = wbase + ks * 8192;
        bf16x8 whi = *(const bf16x8*)(wp);
        bf16x8 wlo = *(const bf16x8*)(wp + 1024);

        bf16x8 xh = *(const bf16x8*)(xsc + addr);
        bf16x8 xl = *(const bf16x8*)(xsc + addr + XLO_BYTES);
        acc[0] = __builtin_amdgcn_mfma_f32_32x32x16_bf16(whi, xh, acc[0], 0, 0, 0);
        acc[0] = __builtin_amdgcn_mfma_f32_32x32x16_bf16(wlo, xh, acc[0], 0, 0, 0);
        acc[0] = __builtin_amdgcn_mfma_f32_32x32x16_bf16(whi, xl, acc[0], 0, 0, 0);
        if (nt1v) {
            bf16x8 xh1 = *(const bf16x8*)(xsc + addr + 4864);             // +2 p-rows
            bf16x8 xl1 = *(const bf16x8*)(xsc + addr + 4864 + XLO_BYTES);
            acc[1] = __builtin_amdgcn_mfma_f32_32x32x16_bf16(whi, xh1, acc[1], 0, 0, 0);
            acc[1] = __builtin_amdgcn_mfma_f32_32x32x16_bf16(wlo, xh1, acc[1], 0, 0, 0);
            acc[1] = __builtin_amdgcn_mfma_f32_32x32x16_bf16(whi, xl1, acc[1], 0, 0, 0);
        }
    }

    // ---- bias add: channel = wv*32 + (reg&3) + 8*(reg>>2) + 4*lhi ----------
    {
        f32x4 bv[4];
#pragma unroll
        for (int j = 0; j < 4; ++j)
            bv[j] = *(const f32x4*)(bias + wv * 32 + lhi * 4 + j * 8);
#pragma unroll
        for (int nt = 0; nt < 2; ++nt)
#pragma unroll
            for (int reg = 0; reg < 16; ++reg)
                acc[nt][reg] += bv[reg >> 2][reg & 3];
    }

    __syncthreads();                    // X planes dead -> overlay reduce bufs
    float* red1  = (float*)smem;        // [64 pos][4 waves] max
    float* red2  = (float*)(smem + 1024);// [64 pos][4 waves] sum
    float* cfill = (float*)(smem + 2048);// [128] const vector

    if (tid < 128) cfill[tid] = wsc[tid];

    // ---- per-position max: in-lane over 16 regs, shfl over lhi, LDS x4 -----
#pragma unroll
    for (int nt = 0; nt < 2; ++nt) {
        float m = acc[nt][0];
#pragma unroll
        for (int reg = 1; reg < 16; ++reg) m = fmaxf(m, acc[nt][reg]);
        m = fmaxf(m, __shfl_xor(m, 32));
        if (lhi == 0) red1[(nt * 32 + l31) * 4 + wv] = m;
    }
    __syncthreads();

    float gm[2];
#pragma unroll
    for (int nt = 0; nt < 2; ++nt) {
        f32x4 v = *(const f32x4*)&red1[(nt * 32 + l31) * 4];
        gm[nt] = fmaxf(fmaxf(v[0], v[1]), fmaxf(v[2], v[3]));
    }

    // ---- exp + per-position sum --------------------------------------------
#pragma unroll
    for (int nt = 0; nt < 2; ++nt) {
        float s = 0.f;
#pragma unroll
        for (int reg = 0; reg < 16; ++reg) {
            float e = __expf(acc[nt][reg] - gm[nt]);
            acc[nt][reg] = e;
            s += e;
        }
        s += __shfl_xor(s, 32);
        if (lhi == 0) red2[(nt * 32 + l31) * 4 + wv] = s;
    }
    __syncthreads();

    float inv[2];
#pragma unroll
    for (int nt = 0; nt < 2; ++nt) {
        f32x4 v = *(const f32x4*)&red2[(nt * 32 + l31) * 4];
        inv[nt] = 1.0f / (v[0] + v[1] + v[2] + v[3]);
    }

    // ---- normalize, sigmoid, store: 128B-contiguous per 16 lanes -----------
    {
        f32x4 cv[4];
#pragma unroll
        for (int j = 0; j < 4; ++j)
            cv[j] = *(const f32x4*)(wsc + wv * 32 + lhi * 4 + j * 8);

        int q = q0 + qA;
#pragma unroll
        for (int nt = 0; nt < 2; ++nt) {
            int p = p0 + nt * 2 + dp;
            if (p < 65 && q < 65) {
#pragma unroll
                for (int reg = 0; reg < 16; ++reg) {
                    int c = wv * 32 + 4 * lhi + 8 * (reg >> 2) + (reg & 3);
                    float v  = acc[nt][reg] * inv[nt];
                    float sg = 1.0f / (1.0f + __expf(-2.0f * v));
                    size_t o = ((size_t)(n * 128 + c) * 129 + 2 * p) * 129 + 2 * q;
                    if (q < 64) {
                        float2 pr2 = {sg, cv[reg >> 2][reg & 3]};
                        *(float2*)(out + o) = pr2;
                    } else {
                        out[o] = sg;
                    }
                }
            }
        }
    }

    // ---- merged odd-row const fill: 97 FULL 516B rows per block ------------
    // (cfill visible: written before the red1/red2 barriers above)
    {
        int bid   = (blockIdx.z * 17 + blockIdx.y) * 5 + blockIdx.x;
        int rbase = bid * ROWS_PER_BLOCK;
        int t    = tid & 127;           // column 0..127
        int half = tid >> 7;            // 2 rows in flight
        for (int i = half; i < ROWS_PER_BLOCK; i += 2) {
            int r = rbase + i;
            if (r < ODD_ROWS) {
                int n2 = r >> 13;
                int c2 = (r >> 6) & 127;
                int oh = ((r & 63) << 1) + 1;
                float v = cfill[c2];
                size_t base = ((size_t)(n2 * 128 + c2) * 129 + oh) * 129;
                out[base + t] = v;
                if (t == 127) out[base + 128] = v;
            }
        }
    }
}

extern "C" void kernel_launch(void* const* d_in, const int* in_sizes, int n_in,
                              void* d_out, int out_size, void* d_ws, size_t ws_size,
                              hipStream_t stream) {
    const float* x    = (const float*)d_in[0];
    const float* w    = (const float*)d_in[1];
    const float* bias = (const float*)d_in[2];
    float* out = (float*)d_out;

    ushort_t* wsW = (ushort_t*)d_ws;                          // 512 KB
    float* wsc    = (float*)((char*)d_ws + WSW_BYTES);        // 512 B

    (void)hipFuncSetAttribute((const void*)conv_main_kernel,
                              hipFuncAttributeMaxDynamicSharedMemorySize, SMEM_BYTES);

    prep_w_kernel<<<128, 256, 0, stream>>>(w, wsW);
    prep_const_kernel<<<1, 128, 0, stream>>>(bias, wsc);

    dim3 grid(5, 17, 32);   // q-tiles, p-tiles, n
    conv_main_kernel<<<grid, 256, SMEM_BYTES, stream>>>(x, bias, wsW, wsc, out);
}

// Round 6
// 192.198 us; speedup vs baseline: 1.3645x; 1.0415x over previous
//
#include <hip/hip_runtime.h>
#include <hip/hip_bf16.h>

// ============================================================================
// fused stride-2 "transposed conv" + bias + channel-softmax + sigmoid
//
// PAD==OUT_PAD==1 => odd h or odd w outputs are the constant vector
// sigmoid(2*softmax(bias)). Even-even outputs are a dense 4x4 conv:
//   O[n,c,p,q] = sum_{ic,kh,kw} x[n,ic,p-kh,q-kw]*W[c,ic,kh,kw]
//
// R6: R5 (A=W, B=X, coalesced stores) + K-loop made pipelineable:
// branch-free body (always compute acc[1]) + unroll 8 + VGPR headroom so the
// scheduler prefetches W (L2, ~200cy) and X (LDS, ~120cy) across iterations.
// R5 was latency-bound: all pipes <30% busy, VGPR=36 (no prefetch possible).
// Numerics: bf16 hi/lo split (Whi*Xhi + Wlo*Xhi + Whi*Xlo), fp32 acc.
// ============================================================================

typedef __bf16 bf16x8 __attribute__((ext_vector_type(8)));
typedef float  f32x4  __attribute__((ext_vector_type(4)));
typedef float  f32x16 __attribute__((ext_vector_type(16)));
typedef unsigned short ushort_t;

#define TILE_P 4
#define TILE_Q 16
#define PATCH_R 7                     // TILE_P + 3
#define PATCH_C 19                    // TILE_Q + 3
#define XELEMS (PATCH_R*PATCH_C*64)   // 8512 bf16 per plane
#define XLO_BYTES (XELEMS*2)          // 17024
#define SMEM_BYTES (XELEMS*2*2)       // 34048 -> 4 blocks/CU
#define WSW_BYTES (16*4*4*2*64*16)    // 524288 bytes of W fragments
#define ODD_ROWS (32*128*64)          // 262144 odd output rows
#define ROWS_PER_BLOCK 97             // ceil(262144/2720)

// ---- prep: weight -> 32x32 fragment order, bf16 hi/lo ----------------------
// frag f = ((tap*4+icg)*4+Mt)*2+hl, 1KB each; lane l holds
// W[cout=Mt*32+(l&31)][ic=icg*16+(l>>5)*8+i]  (A-operand: row=l&31, k slice).
__global__ void prep_w_kernel(const float* __restrict__ w, ushort_t* __restrict__ wsW) {
    int slot = blockIdx.x * 256 + threadIdx.x;      // 32768 slots
    int lane = slot & 63;
    int hl   = (slot >> 6) & 1;
    int Mt   = (slot >> 7) & 3;
    int icg  = (slot >> 9) & 3;
    int tap  = slot >> 11;
    int kh = tap >> 2, kw = tap & 3;
    int cout = Mt * 32 + (lane & 31);
    int icb  = icg * 16 + (lane >> 5) * 8;
    bf16x8 v;
#pragma unroll
    for (int i = 0; i < 8; ++i) {
        float f = w[((cout * 64 + icb + i) * 4 + kh) * 4 + kw];
        __bf16 h = (__bf16)f;
        v[i] = hl ? (__bf16)(f - (float)h) : h;
    }
    *(bf16x8*)(wsW + (size_t)slot * 8) = v;   // slot*16 bytes
}

// ---- prep: const vector sigmoid(2*softmax(bias)) ---------------------------
__global__ void prep_const_kernel(const float* __restrict__ bias, float* __restrict__ wsc) {
    __shared__ float red[128];
    int t = threadIdx.x;
    red[t] = bias[t];
    __syncthreads();
    float m = -3.4e38f;
    for (int i = 0; i < 128; ++i) m = fmaxf(m, red[i]);
    float e = __expf(red[t] - m);
    __syncthreads();
    red[t] = e;
    __syncthreads();
    float s = 0.f;
    for (int i = 0; i < 128; ++i) s += red[i];
    float v = e / s;
    wsc[t] = 1.0f / (1.0f + __expf(-2.0f * v));
}

// ---- main ------------------------------------------------------------------
__launch_bounds__(256, 4)
__global__ void conv_main_kernel(const float* __restrict__ x,
                                 const float* __restrict__ bias,
                                 const ushort_t* __restrict__ wsW,
                                 const float* __restrict__ wsc,
                                 float* __restrict__ out) {
    extern __shared__ char smem[];
    ushort_t* xs = (ushort_t*)smem;

    const int tid = threadIdx.x;
    const int n   = blockIdx.z;
    const int p0  = blockIdx.y * TILE_P;
    const int q0  = blockIdx.x * TILE_Q;

    const int lane = tid & 63;
    const int wv   = tid >> 6;       // wave id = Mtile (32 couts)
    const int l31  = lane & 31;
    const int lhi  = lane >> 5;
    const int qA   = l31 & 15;       // B col -> q offset
    const int dp   = l31 >> 4;       // B col -> p offset within Ntile

    // ---- stage X patch hi+lo, single pass ----------------------------------
    const float* xg = x + (size_t)n * 262144;
    for (int grp = tid; grp < PATCH_R * PATCH_C * 8; grp += 256) {
        int r   = grp / (PATCH_C * 8);
        int rem = grp - r * (PATCH_C * 8);
        int g   = rem / PATCH_C;
        int c   = rem - g * PATCH_C;
        int row = p0 + r - 3;
        int col = q0 + c - 3;
        bool ok = (row >= 0) & (row < 64) & (col >= 0) & (col < 64);
        const float* src = xg + (g * 8) * 4096 + row * 64 + col;
        bf16x8 hi, lo;
#pragma unroll
        for (int i = 0; i < 8; ++i) {
            float f = ok ? src[i * 4096] : 0.0f;
            __bf16 h = (__bf16)f;
            hi[i] = h;
            lo[i] = (__bf16)(f - (float)h);
        }
        int slot = ((r * PATCH_C + c) * 8 + (g ^ (c & 7))) * 8;     // elem idx
        *(bf16x8*)(xs + slot)          = hi;
        *(bf16x8*)(xs + XELEMS + slot) = lo;
    }
    __syncthreads();

    // ---- K loop: 64 Ksteps (16 taps x 4 ic16-groups), branch-free ----------
    f32x16 acc[2];
    acc[0] = (f32x16)(0.0f);
    acc[1] = (f32x16)(0.0f);

    const char* wbase = (const char*)wsW + wv * 2048 + lane * 16;
    const char* xsc   = (const char*)smem;

#pragma unroll 8
    for (int ks = 0; ks < 64; ++ks) {
        int tap = ks >> 2, icg = ks & 3;
        int kh = tap >> 2, kw = tap & 3;
        int pc = qA + 3 - kw;
        int pr = dp + 3 - kh;
        int g8 = icg * 2 + lhi;
        int addr = ((((pr * PATCH_C + pc) << 3) + (g8 ^ (pc & 7))) << 4);  // bytes

        const char* wp = wbase + ks * 8192;
        bf16x8 whi = *(const bf16x8*)(wp);
        bf16x8 wlo = *(const bf16x8*)(wp + 1024);
        bf16x8 xh0 = *(const bf16x8*)(xsc + addr);
        bf16x8 xl0 = *(const bf16x8*)(xsc + addr + XLO_BYTES);
        bf16x8 xh1 = *(const bf16x8*)(xsc + addr + 4864);             // +2 p-rows
        bf16x8 xl1 = *(const bf16x8*)(xsc + addr + 4864 + XLO_BYTES);

        acc[0] = __builtin_amdgcn_mfma_f32_32x32x16_bf16(whi, xh0, acc[0], 0, 0, 0);
        acc[1] = __builtin_amdgcn_mfma_f32_32x32x16_bf16(whi, xh1, acc[1], 0, 0, 0);
        acc[0] = __builtin_amdgcn_mfma_f32_32x32x16_bf16(wlo, xh0, acc[0], 0, 0, 0);
        acc[1] = __builtin_amdgcn_mfma_f32_32x32x16_bf16(wlo, xh1, acc[1], 0, 0, 0);
        acc[0] = __builtin_amdgcn_mfma_f32_32x32x16_bf16(whi, xl0, acc[0], 0, 0, 0);
        acc[1] = __builtin_amdgcn_mfma_f32_32x32x16_bf16(whi, xl1, acc[1], 0, 0, 0);
    }

    // ---- bias add: channel = wv*32 + (reg&3) + 8*(reg>>2) + 4*lhi ----------
    {
        f32x4 bv[4];
#pragma unroll
        for (int j = 0; j < 4; ++j)
            bv[j] = *(const f32x4*)(bias + wv * 32 + lhi * 4 + j * 8);
#pragma unroll
        for (int nt = 0; nt < 2; ++nt)
#pragma unroll
            for (int reg = 0; reg < 16; ++reg)
                acc[nt][reg] += bv[reg >> 2][reg & 3];
    }

    __syncthreads();                    // X planes dead -> overlay reduce bufs
    float* red1  = (float*)smem;        // [64 pos][4 waves] max
    float* red2  = (float*)(smem + 1024);// [64 pos][4 waves] sum
    float* cfill = (float*)(smem + 2048);// [128] const vector

    if (tid < 128) cfill[tid] = wsc[tid];

    // ---- per-position max: in-lane over 16 regs, shfl over lhi, LDS x4 -----
#pragma unroll
    for (int nt = 0; nt < 2; ++nt) {
        float m = acc[nt][0];
#pragma unroll
        for (int reg = 1; reg < 16; ++reg) m = fmaxf(m, acc[nt][reg]);
        m = fmaxf(m, __shfl_xor(m, 32));
        if (lhi == 0) red1[(nt * 32 + l31) * 4 + wv] = m;
    }
    __syncthreads();

    float gm[2];
#pragma unroll
    for (int nt = 0; nt < 2; ++nt) {
        f32x4 v = *(const f32x4*)&red1[(nt * 32 + l31) * 4];
        gm[nt] = fmaxf(fmaxf(v[0], v[1]), fmaxf(v[2], v[3]));
    }

    // ---- exp + per-position sum --------------------------------------------
#pragma unroll
    for (int nt = 0; nt < 2; ++nt) {
        float s = 0.f;
#pragma unroll
        for (int reg = 0; reg < 16; ++reg) {
            float e = __expf(acc[nt][reg] - gm[nt]);
            acc[nt][reg] = e;
            s += e;
        }
        s += __shfl_xor(s, 32);
        if (lhi == 0) red2[(nt * 32 + l31) * 4 + wv] = s;
    }
    __syncthreads();

    float inv[2];
#pragma unroll
    for (int nt = 0; nt < 2; ++nt) {
        f32x4 v = *(const f32x4*)&red2[(nt * 32 + l31) * 4];
        inv[nt] = 1.0f / (v[0] + v[1] + v[2] + v[3]);
    }

    // ---- normalize, sigmoid, store: 128B-contiguous per 16 lanes -----------
    {
        f32x4 cv[4];
#pragma unroll
        for (int j = 0; j < 4; ++j)
            cv[j] = *(const f32x4*)(wsc + wv * 32 + lhi * 4 + j * 8);

        int q = q0 + qA;
#pragma unroll
        for (int nt = 0; nt < 2; ++nt) {
            int p = p0 + nt * 2 + dp;
            if (p < 65 && q < 65) {
#pragma unroll
                for (int reg = 0; reg < 16; ++reg) {
                    int c = wv * 32 + 4 * lhi + 8 * (reg >> 2) + (reg & 3);
                    float v  = acc[nt][reg] * inv[nt];
                    float sg = 1.0f / (1.0f + __expf(-2.0f * v));
                    size_t o = ((size_t)(n * 128 + c) * 129 + 2 * p) * 129 + 2 * q;
                    if (q < 64) {
                        float2 pr2 = {sg, cv[reg >> 2][reg & 3]};
                        *(float2*)(out + o) = pr2;
                    } else {
                        out[o] = sg;
                    }
                }
            }
        }
    }

    // ---- merged odd-row const fill: 97 FULL 516B rows per block ------------
    {
        int bid   = (blockIdx.z * 17 + blockIdx.y) * 5 + blockIdx.x;
        int rbase = bid * ROWS_PER_BLOCK;
        int t    = tid & 127;           // column 0..127
        int half = tid >> 7;            // 2 rows in flight
        for (int i = half; i < ROWS_PER_BLOCK; i += 2) {
            int r = rbase + i;
            if (r < ODD_ROWS) {
                int n2 = r >> 13;
                int c2 = (r >> 6) & 127;
                int oh = ((r & 63) << 1) + 1;
                float v = cfill[c2];
                size_t base = ((size_t)(n2 * 128 + c2) * 129 + oh) * 129;
                out[base + t] = v;
                if (t == 127) out[base + 128] = v;
            }
        }
    }
}

extern "C" void kernel_launch(void* const* d_in, const int* in_sizes, int n_in,
                              void* d_out, int out_size, void* d_ws, size_t ws_size,
                              hipStream_t stream) {
    const float* x    = (const float*)d_in[0];
    const float* w    = (const float*)d_in[1];
    const float* bias = (const float*)d_in[2];
    float* out = (float*)d_out;

    ushort_t* wsW = (ushort_t*)d_ws;                          // 512 KB
    float* wsc    = (float*)((char*)d_ws + WSW_BYTES);        // 512 B

    (void)hipFuncSetAttribute((const void*)conv_main_kernel,
                              hipFuncAttributeMaxDynamicSharedMemorySize, SMEM_BYTES);

    prep_w_kernel<<<128, 256, 0, stream>>>(w, wsW);
    prep_const_kernel<<<1, 128, 0, stream>>>(bias, wsc);

    dim3 grid(5, 17, 32);   // q-tiles, p-tiles, n
    conv_main_kernel<<<grid, 256, SMEM_BYTES, stream>>>(x, bias, wsW, wsc, out);
}